// Round 4
// baseline (256.687 us; speedup 1.0000x reference)
//
#include <hip/hip_runtime.h>
#include <hip/hip_bf16.h>
#include <math.h>

// Problem constants (reference: B=64, T=2048, D=256)
#define PB 64
#define PT 2048
#define PD 256
#define PM (PB * PT)

typedef __bf16 bf16x8 __attribute__((ext_vector_type(8)));
typedef short  s16x8  __attribute__((ext_vector_type(8)));
typedef float  f32x4  __attribute__((ext_vector_type(4)));

__device__ __forceinline__ short rne_bf16(float x) {
    unsigned u = __builtin_bit_cast(unsigned, x);
    return (short)((u + 0x7fffu + ((u >> 16) & 1u)) >> 16);
}

// split fp32 -> hi (truncated bf16) + lo (RNE bf16 of remainder)
__device__ __forceinline__ void split_bf16(float x, short& hi, short& lo) {
    unsigned u = __builtin_bit_cast(unsigned, x);
    hi = (short)(u >> 16);
    float hf = __builtin_bit_cast(float, u & 0xffff0000u);
    lo = rne_bf16(x - hf);
}

// ---------------- Kernel P: pack W into hi/lo bf16 B-fragment order --------
// B[k][e] = W[e][k]. mfma_f32_16x16x32_bf16: lane l holds B[k=(l>>4)*8+j][n=l&15].
// flat = ((nt*8 + kt)*64 + quad*16 + n_loc)*8 + j
__global__ __launch_bounds__(256) void prep_kernel(
    const float* __restrict__ W, short* __restrict__ Whi, short* __restrict__ Wlo)
{
    const int idx = blockIdx.x * 256 + threadIdx.x;   // = e*256 + k
    const int e = idx >> 8;
    const int k = idx & 255;
    short h, l;
    split_bf16(W[idx], h, l);
    const int flat = (((e >> 4) * 8 + (k >> 5)) * 64 + ((k & 31) >> 3) * 16 + (e & 15)) * 8 + (k & 7);
    Whi[flat] = h;
    Wlo[flat] = l;
}

// ---------------- Kernel A: scores = attn . tanh(xs @ W^T + b) -------------
// MFMA 16x16x32 bf16, 2-pass xhi.(Whi+Wlo). 512 blocks x 4 row-tiles of 64.
// Register->LDS double-buffered staging keeps xs loads in flight during the
// entire compute phase (HBM duty-cycle fix for the round-3 960 GB/s stall).
#define SBM 64
#define STILES 4

__global__ __launch_bounds__(256, 2) void score_kernel(
    const float* __restrict__ xs, const short* __restrict__ Whi,
    const short* __restrict__ Wlo, const float* __restrict__ bias,
    const float* __restrict__ attn, float* __restrict__ scores)
{
    // A-fragment-packed LDS per tile: [mt(4)][kt(8)][lane(64)][j(8)], XOR-swizzled
    __shared__ short Ah[2][4 * 8 * 64 * 8];   // 2 x 32 KiB
    __shared__ float sred[4][64];

    const int tid = threadIdx.x;
    const int rr  = tid >> 5;        // staging row-in-group 0..7
    const int kb  = tid & 31;        // staging 8-elem k-block

    const int lane = tid & 63;
    const int w    = tid >> 6;
    const int quad = lane >> 4;
    const int nl   = lane & 15;

    float bv[4], av[4];
#pragma unroll
    for (int n = 0; n < 4; ++n) {
        const int col = w * 64 + n * 16 + nl;
        bv[n] = bias[col];
        av[n] = attn[col];
    }

    const int tile0 = blockIdx.x * STILES;
    float4 ra[8], rb[8];             // staging registers (one tile in flight)

    auto issue = [&](int tile) {
        const float* src = xs + (size_t)tile * SBM * PD;
#pragma unroll
        for (int p = 0; p < 8; ++p) {
            const int r = p * 8 + rr;
            ra[p] = *(const float4*)&src[r * PD + kb * 8];
            rb[p] = *(const float4*)&src[r * PD + kb * 8 + 4];
        }
    };
    auto convert_store = [&](int buf) {
#pragma unroll
        for (int p = 0; p < 8; ++p) {
            const int r = p * 8 + rr;
            const float f[8] = {ra[p].x, ra[p].y, ra[p].z, ra[p].w,
                                rb[p].x, rb[p].y, rb[p].z, rb[p].w};
            s16x8 h;
#pragma unroll
            for (int j = 0; j < 8; ++j) h[j] = rne_bf16(f[j]);
            const int mt = r >> 4, m_loc = r & 15;
            const int kt = kb >> 2, q = kb & 3;
            const int msw = m_loc ^ (kb & 7);
            *(s16x8*)&Ah[buf][(((mt * 8 + kt) * 64) + q * 16 + msw) * 8] = h;
        }
    };

    issue(tile0);
    convert_store(0);
    issue(tile0 + 1);                // in flight across tile-0 compute
    __syncthreads();

    for (int t = 0; t < STILES; ++t) {
        const int buf = t & 1;
        f32x4 acc[4][4] = {};        // [mtile][ntile_local]

#pragma unroll 2
        for (int kt = 0; kt < 8; ++kt) {
            bf16x8 bh[4], bl[4];
#pragma unroll
            for (int n = 0; n < 4; ++n) {
                const int nt = w * 4 + n;
                const int bidx = ((nt * 8 + kt) * 64 + lane) * 8;
                bh[n] = *(const bf16x8*)&Whi[bidx];
                bl[n] = *(const bf16x8*)&Wlo[bidx];
            }
            s16x8 ah[4];
            const int msw = nl ^ ((kt * 4 + quad) & 7);
#pragma unroll
            for (int m = 0; m < 4; ++m)
                ah[m] = *(const s16x8*)&Ah[buf][((m * 8 + kt) * 64 + quad * 16 + msw) * 8];
#pragma unroll
            for (int m = 0; m < 4; ++m) {
                const bf16x8 ahm = __builtin_bit_cast(bf16x8, ah[m]);
#pragma unroll
                for (int n = 0; n < 4; ++n) {
                    acc[m][n] = __builtin_amdgcn_mfma_f32_16x16x32_bf16(ahm, bh[n], acc[m][n], 0, 0, 0);
                    acc[m][n] = __builtin_amdgcn_mfma_f32_16x16x32_bf16(ahm, bl[n], acc[m][n], 0, 0, 0);
                }
            }
        }

        // epilogue: +bias, tanh, dot attn over e, reduce across nl
#pragma unroll
        for (int m = 0; m < 4; ++m) {
            float rs[4] = {0.f, 0.f, 0.f, 0.f};
#pragma unroll
            for (int n = 0; n < 4; ++n) {
#pragma unroll
                for (int r = 0; r < 4; ++r) {
                    const float u  = acc[m][n][r] + bv[n];
                    const float e2 = __expf(2.f * u);                 // inf ok -> th=1
                    const float th = 1.f - 2.f * __builtin_amdgcn_rcpf(e2 + 1.f);
                    rs[r] = fmaf(th, av[n], rs[r]);
                }
            }
#pragma unroll
            for (int off = 1; off < 16; off <<= 1) {
#pragma unroll
                for (int r = 0; r < 4; ++r) rs[r] += __shfl_xor(rs[r], off);
            }
            if (nl == 0) {
#pragma unroll
                for (int r = 0; r < 4; ++r) sred[w][m * 16 + quad * 4 + r] = rs[r];
            }
        }
        __syncthreads();
        if (tid < 64)
            scores[(tile0 + t) * SBM + tid] =
                sred[0][tid] + sred[1][tid] + sred[2][tid] + sred[3][tid];

        if (t < STILES - 1) {
            convert_store(buf ^ 1);          // tile t+1 (loads landed long ago)
            if (t < STILES - 2) issue(tile0 + t + 2);
        }
        __syncthreads();
    }
}

// ---------------- Kernel B1: masked softmax over T, in place ---------------
__global__ __launch_bounds__(256) void softmax_kernel(
    const int* __restrict__ mask, float* __restrict__ sw)
{
    const int b    = blockIdx.x;
    const int tid  = threadIdx.x;
    const int lane = tid & 63;
    const int wv   = tid >> 6;
    __shared__ float wred[4];

    float s[8];
    int   v[8];
    float mx = -INFINITY;
#pragma unroll
    for (int i = 0; i < 8; ++i) {
        const int t = i * 256 + tid;
        s[i] = sw[b * PT + t];
        v[i] = mask[b * PT + t];
        if (v[i]) mx = fmaxf(mx, s[i]);
    }
#pragma unroll
    for (int off = 1; off < 64; off <<= 1) mx = fmaxf(mx, __shfl_xor(mx, off));
    if (lane == 0) wred[wv] = mx;
    __syncthreads();
    mx = fmaxf(fmaxf(wred[0], wred[1]), fmaxf(wred[2], wred[3]));
    __syncthreads();

    float p[8];
    float ls = 0.f;
#pragma unroll
    for (int i = 0; i < 8; ++i) {
        p[i] = v[i] ? __expf(s[i] - mx) : 0.f;
        ls += p[i];
    }
#pragma unroll
    for (int off = 1; off < 64; off <<= 1) ls += __shfl_xor(ls, off);
    if (lane == 0) wred[wv] = ls;
    __syncthreads();
    const float inv = 1.f / (wred[0] + wred[1] + wred[2] + wred[3]);
#pragma unroll
    for (int i = 0; i < 8; ++i) sw[b * PT + i * 256 + tid] = p[i] * inv;
}

// ---------------- Kernel B2: chunked weighted moments ----------------------
__global__ __launch_bounds__(256) void moments_kernel(
    const float* __restrict__ xs, const float* __restrict__ w,
    float* __restrict__ part)
{
    const int chunk = blockIdx.x;     // 0..15
    const int b     = blockIdx.y;     // 0..63
    const int tid   = threadIdx.x;
    const int c     = tid & 63;       // float4 column
    const int tq    = tid >> 6;       // 0..3

    __shared__ float  lw[128];
    __shared__ float4 rmu[4][64];
    __shared__ float4 rm2[4][64];

    if (tid < 128) lw[tid] = w[b * PT + chunk * 128 + tid];
    __syncthreads();

    float4 mu = {0.f, 0.f, 0.f, 0.f};
    float4 m2 = {0.f, 0.f, 0.f, 0.f};
#pragma unroll 8
    for (int i = 0; i < 32; ++i) {
        const int tl = tq * 32 + i;
        const float wv = lw[tl];
        const float4 x = *(const float4*)&xs[(b * PT + chunk * 128 + tl) * PD + c * 4];
        mu.x = fmaf(wv, x.x, mu.x); mu.y = fmaf(wv, x.y, mu.y);
        mu.z = fmaf(wv, x.z, mu.z); mu.w = fmaf(wv, x.w, mu.w);
        m2.x = fmaf(wv * x.x, x.x, m2.x); m2.y = fmaf(wv * x.y, x.y, m2.y);
        m2.z = fmaf(wv * x.z, x.z, m2.z); m2.w = fmaf(wv * x.w, x.w, m2.w);
    }
    rmu[tq][c] = mu;
    rm2[tq][c] = m2;
    __syncthreads();

    if (tid < 64) {
        float4 smu = rmu[0][tid], sm2 = rm2[0][tid];
        for (int q = 1; q < 4; ++q) {
            const float4 a = rmu[q][tid], d = rm2[q][tid];
            smu.x += a.x; smu.y += a.y; smu.z += a.z; smu.w += a.w;
            sm2.x += d.x; sm2.y += d.y; sm2.z += d.z; sm2.w += d.w;
        }
        const int base = (b * 16 + chunk) * 512;
        *(float4*)&part[base + tid * 4]       = smu;
        *(float4*)&part[base + 256 + tid * 4] = sm2;
    }
}

// ---------------- Kernel B3: reduce chunks, finalize -----------------------
__global__ __launch_bounds__(256) void finalize_kernel(
    const float* __restrict__ part, float* __restrict__ out)
{
    const int b = blockIdx.x;
    const int d = threadIdx.x;
    float m1 = 0.f, m2 = 0.f;
#pragma unroll
    for (int ch = 0; ch < 16; ++ch) {
        const int base = (b * 16 + ch) * 512;
        m1 += part[base + d];
        m2 += part[base + 256 + d];
    }
    const float var = fmaxf(m2 - m1 * m1, 1e-5f);
    out[b * 512 + d]       = m1;
    out[b * 512 + 256 + d] = sqrtf(var);
}

extern "C" void kernel_launch(void* const* d_in, const int* in_sizes, int n_in,
                              void* d_out, int out_size, void* d_ws, size_t ws_size,
                              hipStream_t stream) {
    const float* xs   = (const float*)d_in[0];
    const int*   mask = (const int*)d_in[1];
    // d_in[2] = mask2, unused
    const float* W    = (const float*)d_in[3];
    const float* bias = (const float*)d_in[4];
    const float* attn = (const float*)d_in[5];
    float* out = (float*)d_out;

    float* scores = (float*)d_ws;                    // PB*PT floats
    float* part   = scores + PB * PT;                // PB*16*512 floats
    short* Whi    = (short*)(part + PB * 16 * 512);  // 65536 shorts
    short* Wlo    = Whi + PD * PD;                   // 65536 shorts

    prep_kernel<<<PD * PD / 256, 256, 0, stream>>>(W, Whi, Wlo);
    score_kernel<<<PM / (SBM * STILES), 256, 0, stream>>>(xs, Whi, Wlo, bias, attn, scores);
    softmax_kernel<<<PB, 256, 0, stream>>>(mask, scores);
    moments_kernel<<<dim3(16, PB), 256, 0, stream>>>(xs, scores, part);
    finalize_kernel<<<PB, 256, 0, stream>>>(part, out);
}